// Round 9
// baseline (378.340 us; speedup 1.0000x reference)
//
#include <hip/hip_runtime.h>

typedef short short8 __attribute__((ext_vector_type(8)));
typedef float floatx16 __attribute__((ext_vector_type(16)));
typedef float floatx4 __attribute__((ext_vector_type(4)));

#define ROWS 81
#define CDIM 256
// LDS layout: XT bf16 [81][256] p-major rows (r=p*9+m), swizzle SWX, stride 512B
//             QT bf16 [96][128] (padded rows), swizzle (r&15)<<4, stride 256B
//             SC f32 4 partial score tiles [16][16]
//             AB bf16 attn [16][16]
#define XT   0
#define QT   41472
#define SC   66048
#define AB   70144
#define TOT  70656

#define SWX(r) ((((r) & 15) << 4) ^ (((r) & 8) << 3))

__device__ __forceinline__ unsigned short f2bf(float f) {
    union { float f; unsigned int u; } v; v.f = f;
    return (unsigned short)((v.u + 0x7FFFu + ((v.u >> 16) & 1u)) >> 16);
}

__device__ __forceinline__ unsigned int cvtpk(float lo, float hi) {
    unsigned int r;
    asm("v_cvt_pk_bf16_f32 %0, %1, %2" : "=v"(r) : "v"(lo), "v"(hi));
    return r;
}

__global__ void wconv_kernel(const float* __restrict__ W,
                             unsigned short* __restrict__ Wb, int n) {
    int i = blockIdx.x * 256 + threadIdx.x;
    if (i < n) Wb[i] = f2bf(W[i]);
}

__device__ __forceinline__ void stage_store(char* smem, int k, float4 a0, float4 a1) {
    int gr = k >> 5;
    int c0 = (k & 31) * 8;            // f32 col base
    int hh = gr / 9, ww = gr - hh * 9;
    int p = (hh % 3) * 3 + (ww % 3);
    int m = (hh / 3) * 3 + (ww / 3);
    int r = p * 9 + m;
    uint4 v;
    v.x = cvtpk(a0.x, a0.y);
    v.y = cvtpk(a0.z, a0.w);
    v.z = cvtpk(a1.x, a1.y);
    v.w = cvtpk(a1.z, a1.w);
    *(uint4*)(smem + XT + r * 512 + ((c0 * 2) ^ SWX(r))) = v;
}

__global__ __launch_bounds__(512, 4)
void attn_kernel(const float* __restrict__ x,
                 const unsigned short* __restrict__ Wb,
                 const float* __restrict__ b_fc,
                 const int* __restrict__ block_idx,
                 const int* __restrict__ match_vec,
                 float* __restrict__ out)
{
    __shared__ __align__(16) char smem[TOT];
    const int b     = blockIdx.x;
    const int t     = threadIdx.x;
    const int lane  = t & 63;
    const int wave  = t >> 6;       // 0..7
    const int l15   = lane & 15;
    const int kg    = lane >> 4;    // 0..3
    const int l31   = lane & 31;
    const int khalf = lane >> 5;    // 0..1

    // ---- anti-convoy stagger: half-delay one member of each initial
    //      co-resident pair (covers both (2i,2i+1) and (i,i+256) pairings).
    if (b < 512 && (((b ^ (b >> 8)) & 1) != 0)) {
        __builtin_amdgcn_s_sleep(100);
        __builtin_amdgcn_s_sleep(100);
    }

    int cm = 0;
    if (t < 9) cm = match_vec[block_idx[b]];

    // ---- proj tiling: wave -> 48 rows x 32 h-cols (halves XT read redundancy)
    const int rh = (wave & 1) * 48;       // row half
    const int hg = (wave >> 1) * 32;      // h group (32 cols)

    // W^T B-fragments: 2 sets of 16 h-cols (L2-hot), 64 VGPR
    short8 wfrag[2][8];
#pragma unroll
    for (int s2 = 0; s2 < 2; ++s2) {
        const unsigned short* wr = Wb + (hg + s2 * 16 + l15) * CDIM + kg * 8;
#pragma unroll
        for (int ks = 0; ks < 8; ++ks)
            wfrag[s2][ks] = *(const short8*)(wr + ks * 32);
    }
    float bias2[2];
    bias2[0] = b_fc[hg + l15];
    bias2[1] = b_fc[hg + 16 + l15];

    // ---- stage x -> XT bf16, p-major rows, swizzled, cvt_pk conversion ----
    {
        const float* xb = x + (size_t)b * (ROWS * CDIM);
        for (int k = t; k < ROWS * 32; k += 512) {
            float4 a0 = *(const float4*)(xb + k * 8);
            float4 a1 = *(const float4*)(xb + k * 8 + 4);
            stage_store(smem, k, a0, a1);
        }
    }
    __syncthreads();   // B0: XT ready

    // ---- proj: q[96x128] = x @ W^T via 16x16x32: 3 row-tiles x 2 h-sets x 8 k ----
    {
        floatx4 acc[3][2];
#pragma unroll
        for (int ii = 0; ii < 3; ++ii)
#pragma unroll
            for (int s2 = 0; s2 < 2; ++s2)
#pragma unroll
                for (int j = 0; j < 4; ++j) acc[ii][s2][j] = 0.f;
#pragma unroll
        for (int ks = 0; ks < 8; ++ks) {
            int cb = ks * 64 + kg * 16;       // byte offset of k-chunk
#pragma unroll
            for (int tile = 0; tile < 3; ++tile) {
                int r = rh + tile * 16 + l15;
                short8 a = *(const short8*)(smem + XT + r * 512 + (cb ^ SWX(r)));
                acc[tile][0] = __builtin_amdgcn_mfma_f32_16x16x32_bf16(a, wfrag[0][ks], acc[tile][0], 0, 0, 0);
                acc[tile][1] = __builtin_amdgcn_mfma_f32_16x16x32_bf16(a, wfrag[1][ks], acc[tile][1], 0, 0, 0);
            }
        }
#pragma unroll
        for (int tile = 0; tile < 3; ++tile)
#pragma unroll
            for (int s2 = 0; s2 < 2; ++s2) {
                int h2 = (hg + s2 * 16 + l15) * 2;
#pragma unroll
                for (int reg = 0; reg < 4; ++reg) {
                    int r = rh + tile * 16 + kg * 4 + reg;   // 0..95, QT padded
                    *(unsigned short*)(smem + QT + r * 256 + (h2 ^ ((r & 15) << 4))) =
                        f2bf(acc[tile][s2][reg] + bias2[s2]);
                }
            }
    }
    __syncthreads();   // B1: q ready

    // ---- gram partials: waves 0..3, 9 k-chunks each, no atomics ----
    if (wave < 4) {
        floatx4 g;
#pragma unroll
        for (int ii = 0; ii < 4; ++ii) g[ii] = 0.f;
        int nc = (l15 < 9) ? l15 : 8;
#pragma unroll
        for (int s = 0; s < 9; ++s) {
            int ks = wave + s * 4;            // 0..35
            int kk = ks * 32 + kg * 8;        // bf16 index in [0,1152)
            int p  = kk >> 7;
            int h0 = (kk & 127) * 2;
            int row = p * 9 + nc;
            short8 f = *(const short8*)(smem + QT + row * 256 + (h0 ^ ((row & 15) << 4)));
            g = __builtin_amdgcn_mfma_f32_16x16x32_bf16(f, f, g, 0, 0, 0);
        }
        float* sc = (float*)(smem + SC + wave * 1024);
#pragma unroll
        for (int reg = 0; reg < 4; ++reg)
            sc[(kg * 4 + reg) * 16 + l15] = g[reg];
    }
    __syncthreads();   // B2: partials ready

    // ---- masked softmax rows 0..8 (sum 4 partials); attn bf16 [16][16] ----
    if (t < 9) {
        const float scale = 0.029462782549439483f;   // (128*9)^-0.5
        const float* sc0 = (const float*)(smem + SC);
        const float* sc1 = (const float*)(smem + SC + 1024);
        const float* sc2 = (const float*)(smem + SC + 2048);
        const float* sc3 = (const float*)(smem + SC + 3072);
        float s[9];
        float mx = -1e30f;
#pragma unroll
        for (int m = 0; m < 9; ++m) {
            int o = t * 16 + m;
            float v = (sc0[o] + sc1[o] + sc2[o] + sc3[o]) * scale;
            if (m == t && cm != 1) v -= 100.f;
            s[m] = v;
            mx = fmaxf(mx, v);
        }
        float sum = 0.f;
#pragma unroll
        for (int m = 0; m < 9; ++m) { s[m] = __expf(s[m] - mx); sum += s[m]; }
        float inv = 1.f / sum;
        unsigned short* ab = (unsigned short*)(smem + AB) + t * 16;
#pragma unroll
        for (int m = 0; m < 9; ++m) ab[m] = f2bf(s[m] * inv);
#pragma unroll
        for (int m = 9; m < 16; ++m) ab[m] = 0;
    }
    __syncthreads();   // B3: attn ready

    // ---- out^T = v^T @ attn^T via 32x32x16; 9 d-tiles/wave; zero16 C-in ----
    {
        const int n  = l31;
        const int nm = (n < 9) ? n : 0;
        short8 bf = *(const short8*)(smem + AB + nm * 32 + khalf * 16);
        floatx16 zero16;
#pragma unroll
        for (int ii = 0; ii < 16; ++ii) zero16[ii] = 0.f;
        float* ob = out + (size_t)b * (ROWS * CDIM);
        int hh = 0, ww = 0;
        if (n < 9) { hh = (n / 3) * 3; ww = (n % 3) * 3; }
#pragma unroll
        for (int tt = 0; tt < 9; ++tt) {
            int tile = wave * 9 + tt;
            int p = tile >> 3;                    // pixel (uniform per tile)
            int c = (tile & 7) * 32 + l31;        // f32 col within pixel
            short8 af;
#pragma unroll
            for (int j = 0; j < 8; ++j) {
                int mm = khalf * 8 + j; if (mm > 8) mm = 8;   // attn cols >8 are 0
                int row = p * 9 + mm;                          // consecutive rows
                af[j] = *(const short*)(smem + XT + row * 512 + ((c * 2) ^ SWX(row)));
            }
            floatx16 dacc = __builtin_amdgcn_mfma_f32_32x32x16_bf16(af, bf, zero16, 0, 0, 0);
            if (n < 9) {
#pragma unroll
                for (int q2 = 0; q2 < 4; ++q2) {
                    int c0 = (tile & 7) * 32 + q2 * 8 + khalf * 4;
                    int gr = (hh + p / 3) * 9 + (ww + p % 3);
                    *(float4*)(ob + gr * CDIM + c0) =
                        make_float4(dacc[q2 * 4 + 0], dacc[q2 * 4 + 1],
                                    dacc[q2 * 4 + 2], dacc[q2 * 4 + 3]);
                }
            }
        }
    }
}

extern "C" void kernel_launch(void* const* d_in, const int* in_sizes, int n_in,
                              void* d_out, int out_size, void* d_ws, size_t ws_size,
                              hipStream_t stream) {
    const float* x    = (const float*)d_in[0];
    const float* W    = (const float*)d_in[1];
    const float* bfc  = (const float*)d_in[2];
    const int*   bidx = (const int*)d_in[3];
    const int*   mvec = (const int*)d_in[4];
    float* outp = (float*)d_out;
    unsigned short* Wb = (unsigned short*)d_ws;

    int nW = in_sizes[1];                       // 128*256
    wconv_kernel<<<(nW + 255) / 256, 256, 0, stream>>>(W, Wb, nW);

    int B = in_sizes[0] / (ROWS * CDIM);        // 8192
    attn_kernel<<<B, 512, 0, stream>>>(x, Wb, bfc, bidx, mvec, outp);
}

// Round 10
// 345.539 us; speedup vs baseline: 1.0949x; 1.0949x over previous
//
#include <hip/hip_runtime.h>

typedef short short8 __attribute__((ext_vector_type(8)));
typedef float floatx16 __attribute__((ext_vector_type(16)));
typedef float floatx4 __attribute__((ext_vector_type(4)));

#define ROWS 81
#define CDIM 256
// LDS layout: XT bf16 [81][256] p-major rows (r=p*9+m), swizzle SWX, stride 512B
//             QT bf16 [96][128] (padded rows), swizzle (r&15)<<4, stride 256B
//             SC f32 4 partial score tiles [16][16]
//             AB bf16 attn [16][16]
#define XT   0
#define QT   41472
#define SC   66048
#define AB   70144
#define TOT  70656

#define SWX(r) ((((r) & 15) << 4) ^ (((r) & 8) << 3))

__device__ __forceinline__ unsigned short f2bf(float f) {
    union { float f; unsigned int u; } v; v.f = f;
    return (unsigned short)((v.u + 0x7FFFu + ((v.u >> 16) & 1u)) >> 16);
}

__device__ __forceinline__ unsigned int cvtpk(float lo, float hi) {
    unsigned int r;
    asm("v_cvt_pk_bf16_f32 %0, %1, %2" : "=v"(r) : "v"(lo), "v"(hi));
    return r;
}

__global__ void wconv_kernel(const float* __restrict__ W,
                             unsigned short* __restrict__ Wb, int n) {
    int i = blockIdx.x * 256 + threadIdx.x;
    if (i < n) Wb[i] = f2bf(W[i]);
}

__device__ __forceinline__ void stage_store(char* smem, int k, float4 a0, float4 a1) {
    int gr = k >> 5;
    int c0 = (k & 31) * 8;            // f32 col base
    int hh = gr / 9, ww = gr - hh * 9;
    int p = (hh % 3) * 3 + (ww % 3);
    int m = (hh / 3) * 3 + (ww / 3);
    int r = p * 9 + m;
    uint4 v;
    v.x = cvtpk(a0.x, a0.y);
    v.y = cvtpk(a0.z, a0.w);
    v.z = cvtpk(a1.x, a1.y);
    v.w = cvtpk(a1.z, a1.w);
    *(uint4*)(smem + XT + r * 512 + ((c0 * 2) ^ SWX(r))) = v;
}

__global__ __launch_bounds__(512, 2)
void attn_kernel(const float* __restrict__ x,
                 const unsigned short* __restrict__ Wb,
                 const float* __restrict__ b_fc,
                 const int* __restrict__ block_idx,
                 const int* __restrict__ match_vec,
                 float* __restrict__ out)
{
    __shared__ __align__(16) char smem[TOT];
    const int b     = blockIdx.x;
    const int t     = threadIdx.x;
    const int lane  = t & 63;
    const int wave  = t >> 6;       // 0..7
    const int l15   = lane & 15;
    const int kg    = lane >> 4;    // 0..3
    const int l31   = lane & 31;
    const int khalf = lane >> 5;    // 0..1

    int cm = 0;
    if (t < 9) cm = match_vec[block_idx[b]];

    // ---- proj tiling: wave -> 48 rows x 32 h-cols (halves XT read redundancy)
    const int rh = (wave & 1) * 48;       // row half
    const int hg = (wave >> 1) * 32;      // h group (32 cols)

    // W^T B-fragments: 2 sets of 16 h-cols (L2-hot)
    short8 wfrag[2][8];
#pragma unroll
    for (int s2 = 0; s2 < 2; ++s2) {
        const unsigned short* wr = Wb + (hg + s2 * 16 + l15) * CDIM + kg * 8;
#pragma unroll
        for (int ks = 0; ks < 8; ++ks)
            wfrag[s2][ks] = *(const short8*)(wr + ks * 32);
    }
    float bias2[2];
    bias2[0] = b_fc[hg + l15];
    bias2[1] = b_fc[hg + 16 + l15];

    // ---- stage x -> XT: issue ALL loads first (one HBM latency), then store ----
    {
        const float* xb = x + (size_t)b * (ROWS * CDIM);
        float4 a0[5], a1[5], t0, t1;
#pragma unroll
        for (int j = 0; j < 5; ++j) {
            int k = t + 512 * j;
            a0[j] = *(const float4*)(xb + k * 8);
            a1[j] = *(const float4*)(xb + k * 8 + 4);
        }
        const bool tail = (t < 32);
        if (tail) {
            t0 = *(const float4*)(xb + (2560 + t) * 8);
            t1 = *(const float4*)(xb + (2560 + t) * 8 + 4);
        }
#pragma unroll
        for (int j = 0; j < 5; ++j) stage_store(smem, t + 512 * j, a0[j], a1[j]);
        if (tail) stage_store(smem, 2560 + t, t0, t1);
    }
    __syncthreads();   // B0: XT ready

    // ---- proj: q[96x128] = x @ W^T via 16x16x32: 3 row-tiles x 2 h-sets x 8 k ----
    {
        floatx4 acc[3][2];
#pragma unroll
        for (int ii = 0; ii < 3; ++ii)
#pragma unroll
            for (int s2 = 0; s2 < 2; ++s2)
#pragma unroll
                for (int j = 0; j < 4; ++j) acc[ii][s2][j] = 0.f;
#pragma unroll
        for (int ks = 0; ks < 8; ++ks) {
            int cb = ks * 64 + kg * 16;       // byte offset of k-chunk
#pragma unroll
            for (int tile = 0; tile < 3; ++tile) {
                int r = rh + tile * 16 + l15;
                short8 a = *(const short8*)(smem + XT + r * 512 + (cb ^ SWX(r)));
                acc[tile][0] = __builtin_amdgcn_mfma_f32_16x16x32_bf16(a, wfrag[0][ks], acc[tile][0], 0, 0, 0);
                acc[tile][1] = __builtin_amdgcn_mfma_f32_16x16x32_bf16(a, wfrag[1][ks], acc[tile][1], 0, 0, 0);
            }
        }
#pragma unroll
        for (int tile = 0; tile < 3; ++tile)
#pragma unroll
            for (int s2 = 0; s2 < 2; ++s2) {
                int h2 = (hg + s2 * 16 + l15) * 2;
#pragma unroll
                for (int reg = 0; reg < 4; ++reg) {
                    int r = rh + tile * 16 + kg * 4 + reg;   // 0..95, QT padded
                    *(unsigned short*)(smem + QT + r * 256 + (h2 ^ ((r & 15) << 4))) =
                        f2bf(acc[tile][s2][reg] + bias2[s2]);
                }
            }
    }
    __syncthreads();   // B1: q ready

    // ---- gram partials: waves 0..3, 9 k-chunks each, no atomics ----
    if (wave < 4) {
        floatx4 g;
#pragma unroll
        for (int ii = 0; ii < 4; ++ii) g[ii] = 0.f;
        int nc = (l15 < 9) ? l15 : 8;
#pragma unroll
        for (int s = 0; s < 9; ++s) {
            int ks = wave + s * 4;            // 0..35
            int kk = ks * 32 + kg * 8;        // bf16 index in [0,1152)
            int p  = kk >> 7;
            int h0 = (kk & 127) * 2;
            int row = p * 9 + nc;
            short8 f = *(const short8*)(smem + QT + row * 256 + (h0 ^ ((row & 15) << 4)));
            g = __builtin_amdgcn_mfma_f32_16x16x32_bf16(f, f, g, 0, 0, 0);
        }
        float* sc = (float*)(smem + SC + wave * 1024);
#pragma unroll
        for (int reg = 0; reg < 4; ++reg)
            sc[(kg * 4 + reg) * 16 + l15] = g[reg];
    }
    __syncthreads();   // B2: partials ready

    // ---- masked softmax rows 0..8 (sum 4 partials); attn bf16 [16][16] ----
    if (t < 9) {
        const float scale = 0.029462782549439483f;   // (128*9)^-0.5
        const float* sc0 = (const float*)(smem + SC);
        const float* sc1 = (const float*)(smem + SC + 1024);
        const float* sc2 = (const float*)(smem + SC + 2048);
        const float* sc3 = (const float*)(smem + SC + 3072);
        float s[9];
        float mx = -1e30f;
#pragma unroll
        for (int m = 0; m < 9; ++m) {
            int o = t * 16 + m;
            float v = (sc0[o] + sc1[o] + sc2[o] + sc3[o]) * scale;
            if (m == t && cm != 1) v -= 100.f;
            s[m] = v;
            mx = fmaxf(mx, v);
        }
        float sum = 0.f;
#pragma unroll
        for (int m = 0; m < 9; ++m) { s[m] = __expf(s[m] - mx); sum += s[m]; }
        float inv = 1.f / sum;
        unsigned short* ab = (unsigned short*)(smem + AB) + t * 16;
#pragma unroll
        for (int m = 0; m < 9; ++m) ab[m] = f2bf(s[m] * inv);
#pragma unroll
        for (int m = 9; m < 16; ++m) ab[m] = 0;
    }
    __syncthreads();   // B3: attn ready

    // ---- out^T = v^T @ attn^T via 32x32x16; 9 d-tiles/wave; zero16 C-in ----
    {
        const int n  = l31;
        const int nm = (n < 9) ? n : 0;
        short8 bf = *(const short8*)(smem + AB + nm * 32 + khalf * 16);
        floatx16 zero16;
#pragma unroll
        for (int ii = 0; ii < 16; ++ii) zero16[ii] = 0.f;
        float* ob = out + (size_t)b * (ROWS * CDIM);
        int hh = 0, ww = 0;
        if (n < 9) { hh = (n / 3) * 3; ww = (n % 3) * 3; }
#pragma unroll
        for (int tt = 0; tt < 9; ++tt) {
            int tile = wave * 9 + tt;
            int p = tile >> 3;                    // pixel (uniform per tile)
            int c = (tile & 7) * 32 + l31;        // f32 col within pixel
            short8 af;
#pragma unroll
            for (int j = 0; j < 8; ++j) {
                int mm = khalf * 8 + j; if (mm > 8) mm = 8;   // attn cols >8 are 0
                int row = p * 9 + mm;                          // consecutive rows
                af[j] = *(const short*)(smem + XT + row * 512 + ((c * 2) ^ SWX(row)));
            }
            floatx16 dacc = __builtin_amdgcn_mfma_f32_32x32x16_bf16(af, bf, zero16, 0, 0, 0);
            if (n < 9) {
#pragma unroll
                for (int q2 = 0; q2 < 4; ++q2) {
                    int c0 = (tile & 7) * 32 + q2 * 8 + khalf * 4;
                    int gr = (hh + p / 3) * 9 + (ww + p % 3);
                    *(float4*)(ob + gr * CDIM + c0) =
                        make_float4(dacc[q2 * 4 + 0], dacc[q2 * 4 + 1],
                                    dacc[q2 * 4 + 2], dacc[q2 * 4 + 3]);
                }
            }
        }
    }
}

extern "C" void kernel_launch(void* const* d_in, const int* in_sizes, int n_in,
                              void* d_out, int out_size, void* d_ws, size_t ws_size,
                              hipStream_t stream) {
    const float* x    = (const float*)d_in[0];
    const float* W    = (const float*)d_in[1];
    const float* bfc  = (const float*)d_in[2];
    const int*   bidx = (const int*)d_in[3];
    const int*   mvec = (const int*)d_in[4];
    float* outp = (float*)d_out;
    unsigned short* Wb = (unsigned short*)d_ws;

    int nW = in_sizes[1];                       // 128*256
    wconv_kernel<<<(nW + 255) / 256, 256, 0, stream>>>(W, Wb, nW);

    int B = in_sizes[0] / (ROWS * CDIM);        // 8192
    attn_kernel<<<B, 512, 0, stream>>>(x, Wb, bfc, bidx, mvec, outp);
}